// Round 1
// baseline (1810.159 us; speedup 1.0000x reference)
//
#include <hip/hip_runtime.h>
#include <hip/hip_fp16.h>

#define D_DIM 1024
#define E_NUM 4
#define F_DIM 4096
#define NTOK 8192         // B*S = 4*2048
#define MT 64             // tokens per tile
#define FC 256            // F-chunk width
#define KC 256            // K-chunk for X staging
#define FHALF 2048        // F per block (F split in 2)

typedef _Float16 half8_t __attribute__((ext_vector_type(8)));
typedef _Float16 half4_t __attribute__((ext_vector_type(4)));
typedef float floatx4 __attribute__((ext_vector_type(4)));

// ---------------- gating: top-2 expert selection + routing lists ----------------
__global__ __launch_bounds__(256) void gate_kernel(
    const float* __restrict__ x, const float* __restrict__ Wg,
    const float* __restrict__ bg, int* __restrict__ cnt, int* __restrict__ lists)
{
    int wave = threadIdx.x >> 6;
    int lane = threadIdx.x & 63;
    int tok = blockIdx.x * 4 + wave;
    if (tok >= NTOK) return;
    const float* xr = x + (size_t)tok * D_DIM;
    double a0 = 0.0, a1 = 0.0, a2 = 0.0, a3 = 0.0;
    for (int i = lane; i < D_DIM; i += 64) {
        double xv = (double)xr[i];
        const float* wr = Wg + i * 4;
        a0 += xv * (double)wr[0];
        a1 += xv * (double)wr[1];
        a2 += xv * (double)wr[2];
        a3 += xv * (double)wr[3];
    }
    for (int off = 32; off > 0; off >>= 1) {
        a0 += __shfl_down(a0, off);
        a1 += __shfl_down(a1, off);
        a2 += __shfl_down(a2, off);
        a3 += __shfl_down(a3, off);
    }
    if (lane == 0) {
        double lg[4] = { a0 + (double)bg[0], a1 + (double)bg[1],
                         a2 + (double)bg[2], a3 + (double)bg[3] };
        int i1 = 0;
        for (int e = 1; e < 4; ++e) if (lg[e] > lg[i1]) i1 = e;   // first max wins
        int i2 = -1;
        for (int e = 0; e < 4; ++e) {
            if (e == i1) continue;
            if (i2 < 0 || lg[e] > lg[i2]) i2 = e;
        }
        int p1 = atomicAdd(&cnt[i1], 1);
        lists[i1 * NTOK + p1] = tok;
        int p2 = atomicAdd(&cnt[i2], 1);
        lists[i2 * NTOK + p2] = tok;
    }
}

// ---------------- fused expert MLP: swish(X W1) W2, scatter-add ----------------
__global__ __launch_bounds__(512, 2) void moe_kernel(
    const float* __restrict__ x, const float* __restrict__ W1,
    const float* __restrict__ b1, const float* __restrict__ W2,
    const float* __restrict__ b2, const int* __restrict__ cnt,
    const int* __restrict__ lists, float* __restrict__ out)
{
    __shared__ _Float16 Xs[MT][KC + 8];   // 64 x 264 fp16, padded
    __shared__ _Float16 Hs[MT][FC + 8];
    __shared__ int tks[MT];

    int fhalf = blockIdx.x & 1;
    int bi = blockIdx.x >> 1;

    // map block -> (expert, tile)
    int expert = -1, tile = 0, mcnt = 0;
    int rem = bi;
    for (int e = 0; e < E_NUM; ++e) {
        int n = cnt[e];
        int nb = (n + MT - 1) / MT;
        if (rem < nb) { expert = e; tile = rem; mcnt = min(MT, n - rem * MT); break; }
        rem -= nb;
    }
    if (expert < 0) return;

    if (threadIdx.x < MT) {
        int idx = tile * MT + (int)threadIdx.x;
        tks[threadIdx.x] = lists[expert * NTOK + ((int)threadIdx.x < mcnt ? idx : tile * MT)];
    }
    __syncthreads();

    const float* W1e = W1 + (size_t)expert * D_DIM * F_DIM;
    const float* W2e = W2 + (size_t)expert * F_DIM * D_DIM;
    const float* b1e = b1 + (size_t)expert * F_DIM;
    const float* b2e = b2 + (size_t)expert * D_DIM;

    int w = threadIdx.x >> 6;        // wave 0..7
    int lane = threadIdx.x & 63;
    int quad = lane >> 4;
    int ln = lane & 15;

    floatx4 oacc[4][8];
    #pragma unroll
    for (int mt = 0; mt < 4; ++mt)
        #pragma unroll
        for (int nt = 0; nt < 8; ++nt)
            oacc[mt][nt] = (floatx4){0.f, 0.f, 0.f, 0.f};

    int fbase = fhalf * FHALF;
    int srow = threadIdx.x >> 3;     // staging row 0..63
    int stg  = threadIdx.x & 7;

    for (int fc = 0; fc < FHALF / FC; ++fc) {
        int f0 = fbase + fc * FC;

        floatx4 hacc[4][2];
        #pragma unroll
        for (int mt = 0; mt < 4; ++mt) { hacc[mt][0] = (floatx4){0.f,0.f,0.f,0.f};
                                         hacc[mt][1] = (floatx4){0.f,0.f,0.f,0.f}; }

        for (int kc = 0; kc < D_DIM / KC; ++kc) {
            int k0 = kc * KC;
            // stage X chunk fp32 -> fp16 LDS
            {
                const float* xr = x + (size_t)tks[srow] * D_DIM + k0;
                #pragma unroll
                for (int j = 0; j < 8; ++j) {
                    int c = (stg + j * 8) * 4;
                    float4 v = *(const float4*)(xr + c);
                    half4_t hv = { (_Float16)v.x, (_Float16)v.y,
                                   (_Float16)v.z, (_Float16)v.w };
                    *(half4_t*)&Xs[srow][c] = hv;
                }
            }
            __syncthreads();

            #pragma unroll
            for (int ks = 0; ks < KC / 32; ++ks) {
                int kk = ks * 32 + quad * 8;
                half8_t a[4];
                #pragma unroll
                for (int mt = 0; mt < 4; ++mt)
                    a[mt] = *(const half8_t*)&Xs[mt * 16 + ln][kk];
                #pragma unroll
                for (int nt = 0; nt < 2; ++nt) {
                    int fcol = f0 + w * 32 + nt * 16 + ln;
                    const float* wp = W1e + (size_t)(k0 + kk) * F_DIM + fcol;
                    half8_t b;
                    #pragma unroll
                    for (int j = 0; j < 8; ++j)
                        b[j] = (_Float16)wp[(size_t)j * F_DIM];
                    #pragma unroll
                    for (int mt = 0; mt < 4; ++mt)
                        hacc[mt][nt] = __builtin_amdgcn_mfma_f32_16x16x32_f16(
                            a[mt], b, hacc[mt][nt], 0, 0, 0);
                }
            }
            __syncthreads();
        }

        // bias + swish, H -> LDS (fp16)
        #pragma unroll
        for (int nt = 0; nt < 2; ++nt) {
            int fcol_l = w * 32 + nt * 16 + ln;
            float b1v = b1e[f0 + fcol_l];
            #pragma unroll
            for (int mt = 0; mt < 4; ++mt)
                #pragma unroll
                for (int r = 0; r < 4; ++r) {
                    float v = hacc[mt][nt][r] + b1v;
                    float hs = v / (1.f + __expf(-v));
                    Hs[mt * 16 + quad * 4 + r][fcol_l] = (_Float16)hs;
                }
        }
        __syncthreads();

        // GEMM2: Out += H @ W2[f-range, :]
        #pragma unroll
        for (int ks = 0; ks < FC / 32; ++ks) {
            int kk = ks * 32 + quad * 8;
            half8_t a[4];
            #pragma unroll
            for (int mt = 0; mt < 4; ++mt)
                a[mt] = *(const half8_t*)&Hs[mt * 16 + ln][kk];
            #pragma unroll
            for (int nt = 0; nt < 8; ++nt) {
                int dcol = w * 128 + nt * 16 + ln;
                const float* wp = W2e + (size_t)(f0 + kk) * D_DIM + dcol;
                half8_t b;
                #pragma unroll
                for (int j = 0; j < 8; ++j)
                    b[j] = (_Float16)wp[(size_t)j * D_DIM];
                #pragma unroll
                for (int mt = 0; mt < 4; ++mt)
                    oacc[mt][nt] = __builtin_amdgcn_mfma_f32_16x16x32_f16(
                        a[mt], b, oacc[mt][nt], 0, 0, 0);
            }
        }
        __syncthreads();
    }

    // epilogue: scatter-add (each token has exactly 2 expert contributions)
    #pragma unroll
    for (int mt = 0; mt < 4; ++mt) {
        #pragma unroll
        for (int r = 0; r < 4; ++r) {
            int row = mt * 16 + quad * 4 + r;
            if (row >= mcnt) continue;
            float* orow = out + (size_t)tks[row] * D_DIM;
            #pragma unroll
            for (int nt = 0; nt < 8; ++nt) {
                int dcol = w * 128 + nt * 16 + ln;
                float v = oacc[mt][nt][r];
                if (fhalf == 0) v += b2e[dcol];   // add bias exactly once per (tok,expert)
                atomicAdd(orow + dcol, v);
            }
        }
    }
}

extern "C" void kernel_launch(void* const* d_in, const int* in_sizes, int n_in,
                              void* d_out, int out_size, void* d_ws, size_t ws_size,
                              hipStream_t stream) {
    const float* x  = (const float*)d_in[0];
    const float* Wg = (const float*)d_in[1];
    const float* bg = (const float*)d_in[2];
    const float* W1 = (const float*)d_in[3];
    const float* b1 = (const float*)d_in[4];
    const float* W2 = (const float*)d_in[5];
    const float* b2 = (const float*)d_in[6];
    float* out = (float*)d_out;

    int* cnt   = (int*)d_ws;          // 4 ints
    int* lists = (int*)d_ws + 8;      // 4 * 8192 ints

    hipMemsetAsync(cnt, 0, 16, stream);
    hipMemsetAsync(d_out, 0, (size_t)out_size * sizeof(float), stream);

    gate_kernel<<<NTOK / 4, 256, 0, stream>>>(x, Wg, bg, cnt, lists);

    // worst-case blocks: sum_e ceil(cnt[e]/64) <= 260, x2 F-halves
    moe_kernel<<<520, 512, 0, stream>>>(x, W1, b1, W2, b2, cnt, lists, out);
}

// Round 3
// 1699.841 us; speedup vs baseline: 1.0649x; 1.0649x over previous
//
#include <hip/hip_runtime.h>
#include <hip/hip_fp16.h>

#define D_DIM 1024
#define E_NUM 4
#define F_DIM 4096
#define NTOK 8192         // B*S = 4*2048
#define MT 64             // tokens per tile
#define FC 256            // F-chunk width
#define KC 256            // K-chunk for X staging
#define FHALF 2048        // F per block (F split in 2)

typedef _Float16 half8_t __attribute__((ext_vector_type(8)));
typedef _Float16 half4_t __attribute__((ext_vector_type(4)));
typedef float floatx4 __attribute__((ext_vector_type(4)));

// ---------------- gating: top-2 expert selection + routing lists ----------------
__global__ __launch_bounds__(256) void gate_kernel(
    const float* __restrict__ x, const float* __restrict__ Wg,
    const float* __restrict__ bg, int* __restrict__ cnt, int* __restrict__ lists)
{
    int wave = threadIdx.x >> 6;
    int lane = threadIdx.x & 63;
    int tok = blockIdx.x * 4 + wave;
    if (tok >= NTOK) return;
    const float* xr = x + (size_t)tok * D_DIM;
    double a0 = 0.0, a1 = 0.0, a2 = 0.0, a3 = 0.0;
    #pragma unroll
    for (int it = 0; it < 4; ++it) {
        int i0 = it * 256 + lane * 4;
        float4 xv = *(const float4*)(xr + i0);
        float4 w0 = *(const float4*)(Wg + (size_t)i0 * 4);
        float4 w1 = *(const float4*)(Wg + (size_t)i0 * 4 + 4);
        float4 w2 = *(const float4*)(Wg + (size_t)i0 * 4 + 8);
        float4 w3 = *(const float4*)(Wg + (size_t)i0 * 4 + 12);
        a0 += (double)xv.x * w0.x + (double)xv.y * w1.x
            + (double)xv.z * w2.x + (double)xv.w * w3.x;
        a1 += (double)xv.x * w0.y + (double)xv.y * w1.y
            + (double)xv.z * w2.y + (double)xv.w * w3.y;
        a2 += (double)xv.x * w0.z + (double)xv.y * w1.z
            + (double)xv.z * w2.z + (double)xv.w * w3.z;
        a3 += (double)xv.x * w0.w + (double)xv.y * w1.w
            + (double)xv.z * w2.w + (double)xv.w * w3.w;
    }
    #pragma unroll
    for (int off = 32; off > 0; off >>= 1) {
        a0 += __shfl_down(a0, off);
        a1 += __shfl_down(a1, off);
        a2 += __shfl_down(a2, off);
        a3 += __shfl_down(a3, off);
    }
    if (lane == 0) {
        double lg[4] = { a0 + (double)bg[0], a1 + (double)bg[1],
                         a2 + (double)bg[2], a3 + (double)bg[3] };
        int i1 = 0;
        for (int e = 1; e < 4; ++e) if (lg[e] > lg[i1]) i1 = e;   // first max wins
        int i2 = -1;
        for (int e = 0; e < 4; ++e) {
            if (e == i1) continue;
            if (i2 < 0 || lg[e] > lg[i2]) i2 = e;
        }
        int p1 = atomicAdd(&cnt[i1], 1);
        lists[i1 * NTOK + p1] = tok;
        int p2 = atomicAdd(&cnt[i2], 1);
        lists[i2 * NTOK + p2] = tok;
    }
}

// ---------------- prep: x fp32 -> fp16 ----------------
__global__ __launch_bounds__(256) void cvt_x_kernel(
    const float* __restrict__ x, _Float16* __restrict__ xh)
{
    size_t i = ((size_t)blockIdx.x * 256 + threadIdx.x) * 8;   // 8 elems/thread
    float4 v0 = *(const float4*)(x + i);
    float4 v1 = *(const float4*)(x + i + 4);
    half8_t h = { (_Float16)v0.x, (_Float16)v0.y, (_Float16)v0.z, (_Float16)v0.w,
                  (_Float16)v1.x, (_Float16)v1.y, (_Float16)v1.z, (_Float16)v1.w };
    *(half8_t*)(xh + i) = h;
}

// ---------------- prep: transpose fp32 [z][R][C] -> fp16 [z][C][R] ----------------
__global__ __launch_bounds__(256) void transpose_fp16_kernel(
    const float* __restrict__ src, _Float16* __restrict__ dst, int R, int C)
{
    __shared__ _Float16 t[32][33];
    int c0 = blockIdx.x * 32, r0 = blockIdx.y * 32;
    const float* s = src + (size_t)blockIdx.z * R * C;
    _Float16* d = dst + (size_t)blockIdx.z * R * C;
    #pragma unroll
    for (int i = 0; i < 4; ++i) {
        int r = threadIdx.y + i * 8;
        t[r][threadIdx.x] = (_Float16)s[(size_t)(r0 + r) * C + c0 + threadIdx.x];
    }
    __syncthreads();
    #pragma unroll
    for (int i = 0; i < 4; ++i) {
        int rr = threadIdx.y + i * 8;          // column of src = row of dst
        d[(size_t)(c0 + rr) * R + r0 + threadIdx.x] = t[threadIdx.x][rr];
    }
}

// ---------------- fast fused MLP: fp16 transposed weights ----------------
__global__ __launch_bounds__(512, 2) void moe_fast_kernel(
    const _Float16* __restrict__ xh, const _Float16* __restrict__ W1t,
    const float* __restrict__ b1, const _Float16* __restrict__ W2t,
    const float* __restrict__ b2, const int* __restrict__ cnt,
    const int* __restrict__ lists, float* __restrict__ out)
{
    __shared__ _Float16 Xs[MT][KC + 8];
    __shared__ _Float16 Hs[MT][FC + 8];
    __shared__ int tks[MT];

    int fhalf = blockIdx.x & 1;
    int bi = blockIdx.x >> 1;

    int expert = -1, tile = 0, mcnt = 0;
    int rem = bi;
    for (int e = 0; e < E_NUM; ++e) {
        int n = cnt[e];
        int nb = (n + MT - 1) / MT;
        if (rem < nb) { expert = e; tile = rem; mcnt = min(MT, n - rem * MT); break; }
        rem -= nb;
    }
    if (expert < 0) return;

    if (threadIdx.x < MT) {
        int idx = tile * MT + (int)threadIdx.x;
        tks[threadIdx.x] = lists[expert * NTOK + ((int)threadIdx.x < mcnt ? idx : tile * MT)];
    }
    __syncthreads();

    const _Float16* W1te = W1t + (size_t)expert * D_DIM * F_DIM;  // [F][D]
    const _Float16* W2te = W2t + (size_t)expert * F_DIM * D_DIM;  // [D][F]
    const float* b1e = b1 + (size_t)expert * F_DIM;
    const float* b2e = b2 + (size_t)expert * D_DIM;

    int w = threadIdx.x >> 6;        // wave 0..7
    int lane = threadIdx.x & 63;
    int quad = lane >> 4;
    int ln = lane & 15;
    int mg = w & 1;                  // GEMM1 m-group (rows mg*32..mg*32+31)
    int fg = w >> 1;                 // GEMM1 f-group (cols fg*64..fg*64+63)

    floatx4 oacc[4][8];
    #pragma unroll
    for (int mt = 0; mt < 4; ++mt)
        #pragma unroll
        for (int nt = 0; nt < 8; ++nt)
            oacc[mt][nt] = (floatx4){0.f, 0.f, 0.f, 0.f};

    int fbase = fhalf * FHALF;
    int srow = threadIdx.x >> 3;     // staging row 0..63
    int stg  = threadIdx.x & 7;      // 8 threads/row, 32 halves (64B) each

    for (int fc = 0; fc < FHALF / FC; ++fc) {
        int f0 = fbase + fc * FC;

        floatx4 hacc[2][4];
        #pragma unroll
        for (int mt = 0; mt < 2; ++mt)
            #pragma unroll
            for (int nt = 0; nt < 4; ++nt)
                hacc[mt][nt] = (floatx4){0.f, 0.f, 0.f, 0.f};

        for (int kc = 0; kc < D_DIM / KC; ++kc) {
            int k0 = kc * KC;
            // stage X chunk (fp16) -> LDS: 32 halves per thread, full 256-wide row
            {
                const _Float16* xr = xh + (size_t)tks[srow] * D_DIM + k0 + stg * 32;
                half8_t v0 = *(const half8_t*)(xr);
                half8_t v1 = *(const half8_t*)(xr + 8);
                half8_t v2 = *(const half8_t*)(xr + 16);
                half8_t v3 = *(const half8_t*)(xr + 24);
                *(half8_t*)&Xs[srow][stg * 32]      = v0;
                *(half8_t*)&Xs[srow][stg * 32 + 8]  = v1;
                *(half8_t*)&Xs[srow][stg * 32 + 16] = v2;
                *(half8_t*)&Xs[srow][stg * 32 + 24] = v3;
            }
            __syncthreads();

            #pragma unroll
            for (int ks = 0; ks < KC / 32; ++ks) {
                int kk = ks * 32 + quad * 8;
                half8_t a[2];
                #pragma unroll
                for (int mt = 0; mt < 2; ++mt)
                    a[mt] = *(const half8_t*)&Xs[mg * 32 + mt * 16 + ln][kk];
                #pragma unroll
                for (int nt = 0; nt < 4; ++nt) {
                    int fcol = f0 + fg * 64 + nt * 16 + ln;
                    half8_t b = *(const half8_t*)(W1te + (size_t)fcol * D_DIM + k0 + kk);
                    #pragma unroll
                    for (int mt = 0; mt < 2; ++mt)
                        hacc[mt][nt] = __builtin_amdgcn_mfma_f32_16x16x32_f16(
                            a[mt], b, hacc[mt][nt], 0, 0, 0);
                }
            }
            __syncthreads();
        }

        // bias + swish, H -> LDS (fp16)
        #pragma unroll
        for (int nt = 0; nt < 4; ++nt) {
            int fcol_l = fg * 64 + nt * 16 + ln;
            float b1v = b1e[f0 + fcol_l];
            #pragma unroll
            for (int mt = 0; mt < 2; ++mt)
                #pragma unroll
                for (int r = 0; r < 4; ++r) {
                    float v = hacc[mt][nt][r] + b1v;
                    float hs = v / (1.f + __expf(-v));
                    Hs[mg * 32 + mt * 16 + quad * 4 + r][fcol_l] = (_Float16)hs;
                }
        }
        __syncthreads();

        // GEMM2: Out += H @ W2[f-range, :]
        #pragma unroll
        for (int ks = 0; ks < FC / 32; ++ks) {
            int kk = ks * 32 + quad * 8;
            half8_t a[4];
            #pragma unroll
            for (int mt = 0; mt < 4; ++mt)
                a[mt] = *(const half8_t*)&Hs[mt * 16 + ln][kk];
            #pragma unroll
            for (int nt = 0; nt < 8; ++nt) {
                int dcol = w * 128 + nt * 16 + ln;
                half8_t b = *(const half8_t*)(W2te + (size_t)dcol * F_DIM + f0 + kk);
                #pragma unroll
                for (int mt = 0; mt < 4; ++mt)
                    oacc[mt][nt] = __builtin_amdgcn_mfma_f32_16x16x32_f16(
                        a[mt], b, oacc[mt][nt], 0, 0, 0);
            }
        }
        __syncthreads();
    }

    // epilogue: scatter-add (each token has exactly 2 expert contributions)
    #pragma unroll
    for (int mt = 0; mt < 4; ++mt) {
        #pragma unroll
        for (int r = 0; r < 4; ++r) {
            int row = mt * 16 + quad * 4 + r;
            if (row >= mcnt) continue;
            float* orow = out + (size_t)tks[row] * D_DIM;
            #pragma unroll
            for (int nt = 0; nt < 8; ++nt) {
                int dcol = w * 128 + nt * 16 + ln;
                float v = oacc[mt][nt][r];
                if (fhalf == 0) v += b2e[dcol];   // bias exactly once per (tok,expert)
                atomicAdd(orow + dcol, v);
            }
        }
    }
}

// ---------------- fallback (round-1) kernel: fp32 weights on the fly ----------------
__global__ __launch_bounds__(512, 2) void moe_slow_kernel(
    const float* __restrict__ x, const float* __restrict__ W1,
    const float* __restrict__ b1, const float* __restrict__ W2,
    const float* __restrict__ b2, const int* __restrict__ cnt,
    const int* __restrict__ lists, float* __restrict__ out)
{
    __shared__ _Float16 Xs[MT][KC + 8];
    __shared__ _Float16 Hs[MT][FC + 8];
    __shared__ int tks[MT];

    int fhalf = blockIdx.x & 1;
    int bi = blockIdx.x >> 1;
    int expert = -1, tile = 0, mcnt = 0;
    int rem = bi;
    for (int e = 0; e < E_NUM; ++e) {
        int n = cnt[e];
        int nb = (n + MT - 1) / MT;
        if (rem < nb) { expert = e; tile = rem; mcnt = min(MT, n - rem * MT); break; }
        rem -= nb;
    }
    if (expert < 0) return;

    if (threadIdx.x < MT) {
        int idx = tile * MT + (int)threadIdx.x;
        tks[threadIdx.x] = lists[expert * NTOK + ((int)threadIdx.x < mcnt ? idx : tile * MT)];
    }
    __syncthreads();

    const float* W1e = W1 + (size_t)expert * D_DIM * F_DIM;
    const float* W2e = W2 + (size_t)expert * F_DIM * D_DIM;
    const float* b1e = b1 + (size_t)expert * F_DIM;
    const float* b2e = b2 + (size_t)expert * D_DIM;

    int w = threadIdx.x >> 6;
    int lane = threadIdx.x & 63;
    int quad = lane >> 4;
    int ln = lane & 15;

    floatx4 oacc[4][8];
    #pragma unroll
    for (int mt = 0; mt < 4; ++mt)
        #pragma unroll
        for (int nt = 0; nt < 8; ++nt)
            oacc[mt][nt] = (floatx4){0.f, 0.f, 0.f, 0.f};

    int fbase = fhalf * FHALF;
    int srow = threadIdx.x >> 3;
    int stg  = threadIdx.x & 7;

    for (int fc = 0; fc < FHALF / FC; ++fc) {
        int f0 = fbase + fc * FC;
        floatx4 hacc[4][2];
        #pragma unroll
        for (int mt = 0; mt < 4; ++mt) { hacc[mt][0] = (floatx4){0.f,0.f,0.f,0.f};
                                         hacc[mt][1] = (floatx4){0.f,0.f,0.f,0.f}; }
        for (int kc = 0; kc < D_DIM / KC; ++kc) {
            int k0 = kc * KC;
            {
                const float* xr = x + (size_t)tks[srow] * D_DIM + k0;
                #pragma unroll
                for (int j = 0; j < 8; ++j) {
                    int c = (stg + j * 8) * 4;
                    float4 v = *(const float4*)(xr + c);
                    half4_t hv = { (_Float16)v.x, (_Float16)v.y,
                                   (_Float16)v.z, (_Float16)v.w };
                    *(half4_t*)&Xs[srow][c] = hv;
                }
            }
            __syncthreads();
            #pragma unroll
            for (int ks = 0; ks < KC / 32; ++ks) {
                int kk = ks * 32 + quad * 8;
                half8_t a[4];
                #pragma unroll
                for (int mt = 0; mt < 4; ++mt)
                    a[mt] = *(const half8_t*)&Xs[mt * 16 + ln][kk];
                #pragma unroll
                for (int nt = 0; nt < 2; ++nt) {
                    int fcol = f0 + w * 32 + nt * 16 + ln;
                    const float* wp = W1e + (size_t)(k0 + kk) * F_DIM + fcol;
                    half8_t b;
                    #pragma unroll
                    for (int j = 0; j < 8; ++j)
                        b[j] = (_Float16)wp[(size_t)j * F_DIM];
                    #pragma unroll
                    for (int mt = 0; mt < 4; ++mt)
                        hacc[mt][nt] = __builtin_amdgcn_mfma_f32_16x16x32_f16(
                            a[mt], b, hacc[mt][nt], 0, 0, 0);
                }
            }
            __syncthreads();
        }
        #pragma unroll
        for (int nt = 0; nt < 2; ++nt) {
            int fcol_l = w * 32 + nt * 16 + ln;
            float b1v = b1e[f0 + fcol_l];
            #pragma unroll
            for (int mt = 0; mt < 4; ++mt)
                #pragma unroll
                for (int r = 0; r < 4; ++r) {
                    float v = hacc[mt][nt][r] + b1v;
                    float hs = v / (1.f + __expf(-v));
                    Hs[mt * 16 + quad * 4 + r][fcol_l] = (_Float16)hs;
                }
        }
        __syncthreads();
        #pragma unroll
        for (int ks = 0; ks < FC / 32; ++ks) {
            int kk = ks * 32 + quad * 8;
            half8_t a[4];
            #pragma unroll
            for (int mt = 0; mt < 4; ++mt)
                a[mt] = *(const half8_t*)&Hs[mt * 16 + ln][kk];
            #pragma unroll
            for (int nt = 0; nt < 8; ++nt) {
                int dcol = w * 128 + nt * 16 + ln;
                const float* wp = W2e + (size_t)(f0 + kk) * D_DIM + dcol;
                half8_t b;
                #pragma unroll
                for (int j = 0; j < 8; ++j)
                    b[j] = (_Float16)wp[(size_t)j * D_DIM];
                #pragma unroll
                for (int mt = 0; mt < 4; ++mt)
                    oacc[mt][nt] = __builtin_amdgcn_mfma_f32_16x16x32_f16(
                        a[mt], b, oacc[mt][nt], 0, 0, 0);
            }
        }
        __syncthreads();
    }
    #pragma unroll
    for (int mt = 0; mt < 4; ++mt) {
        #pragma unroll
        for (int r = 0; r < 4; ++r) {
            int row = mt * 16 + quad * 4 + r;
            if (row >= mcnt) continue;
            float* orow = out + (size_t)tks[row] * D_DIM;
            #pragma unroll
            for (int nt = 0; nt < 8; ++nt) {
                int dcol = w * 128 + nt * 16 + ln;
                float v = oacc[mt][nt][r];
                if (fhalf == 0) v += b2e[dcol];
                atomicAdd(orow + dcol, v);
            }
        }
    }
}

extern "C" void kernel_launch(void* const* d_in, const int* in_sizes, int n_in,
                              void* d_out, int out_size, void* d_ws, size_t ws_size,
                              hipStream_t stream) {
    const float* x  = (const float*)d_in[0];
    const float* Wg = (const float*)d_in[1];
    const float* bg = (const float*)d_in[2];
    const float* W1 = (const float*)d_in[3];
    const float* b1 = (const float*)d_in[4];
    const float* W2 = (const float*)d_in[5];
    const float* b2 = (const float*)d_in[6];
    float* out = (float*)d_out;

    // ws layout: [cnt 16B][pad][lists @512B, 128KB][W1t fp16 32MB][W2t fp16 32MB][xh fp16 16MB]
    const size_t OFF_LISTS = 512;
    const size_t OFF_W1T   = 131584;                       // 512 + 4*8192*4
    const size_t OFF_W2T   = OFF_W1T + (size_t)E_NUM * D_DIM * F_DIM * 2;
    const size_t OFF_XH    = OFF_W2T + (size_t)E_NUM * D_DIM * F_DIM * 2;
    const size_t WS_NEED   = OFF_XH + (size_t)NTOK * D_DIM * 2;

    int* cnt   = (int*)d_ws;
    int* lists = (int*)((char*)d_ws + OFF_LISTS);

    hipMemsetAsync(cnt, 0, 16, stream);
    hipMemsetAsync(d_out, 0, (size_t)out_size * sizeof(float), stream);

    gate_kernel<<<NTOK / 4, 256, 0, stream>>>(x, Wg, bg, cnt, lists);

    if (ws_size >= WS_NEED) {
        _Float16* W1t = (_Float16*)((char*)d_ws + OFF_W1T);
        _Float16* W2t = (_Float16*)((char*)d_ws + OFF_W2T);
        _Float16* xh  = (_Float16*)((char*)d_ws + OFF_XH);

        cvt_x_kernel<<<(NTOK * D_DIM) / (256 * 8), 256, 0, stream>>>(x, xh);
        // W1 [E][D][F] -> W1t [E][F][D]
        transpose_fp16_kernel<<<dim3(F_DIM / 32, D_DIM / 32, E_NUM), dim3(32, 8), 0, stream>>>(
            W1, W1t, D_DIM, F_DIM);
        // W2 [E][F][D] -> W2t [E][D][F]
        transpose_fp16_kernel<<<dim3(D_DIM / 32, F_DIM / 32, E_NUM), dim3(32, 8), 0, stream>>>(
            W2, W2t, F_DIM, D_DIM);

        moe_fast_kernel<<<520, 512, 0, stream>>>(xh, W1t, b1, W2t, b2, cnt, lists, out);
    } else {
        moe_slow_kernel<<<520, 512, 0, stream>>>(x, W1, b1, W2, b2, cnt, lists, out);
    }
}

// Round 4
// 1132.749 us; speedup vs baseline: 1.5980x; 1.5006x over previous
//
#include <hip/hip_runtime.h>
#include <hip/hip_fp16.h>

#define D_DIM 1024
#define E_NUM 4
#define F_DIM 4096
#define NTOK 8192         // B*S = 4*2048
#define MT 64             // tokens per tile
#define FC 256            // F-chunk width
#define KC 256            // K-chunk for X staging
#define FHALF 2048        // F per block (F split in 2)

typedef _Float16 half8_t __attribute__((ext_vector_type(8)));
typedef _Float16 half4_t __attribute__((ext_vector_type(4)));
typedef float floatx4 __attribute__((ext_vector_type(4)));

// ---------------- gating: top-2 expert selection + routing lists ----------------
__global__ __launch_bounds__(256) void gate_kernel(
    const float* __restrict__ x, const float* __restrict__ Wg,
    const float* __restrict__ bg, int* __restrict__ cnt, int* __restrict__ lists)
{
    int wave = threadIdx.x >> 6;
    int lane = threadIdx.x & 63;
    int tok = blockIdx.x * 4 + wave;
    if (tok >= NTOK) return;
    const float* xr = x + (size_t)tok * D_DIM;
    double a0 = 0.0, a1 = 0.0, a2 = 0.0, a3 = 0.0;
    #pragma unroll
    for (int it = 0; it < 4; ++it) {
        int i0 = it * 256 + lane * 4;
        float4 xv = *(const float4*)(xr + i0);
        float4 w0 = *(const float4*)(Wg + (size_t)i0 * 4);
        float4 w1 = *(const float4*)(Wg + (size_t)i0 * 4 + 4);
        float4 w2 = *(const float4*)(Wg + (size_t)i0 * 4 + 8);
        float4 w3 = *(const float4*)(Wg + (size_t)i0 * 4 + 12);
        a0 += (double)xv.x * w0.x + (double)xv.y * w1.x
            + (double)xv.z * w2.x + (double)xv.w * w3.x;
        a1 += (double)xv.x * w0.y + (double)xv.y * w1.y
            + (double)xv.z * w2.y + (double)xv.w * w3.y;
        a2 += (double)xv.x * w0.z + (double)xv.y * w1.z
            + (double)xv.z * w2.z + (double)xv.w * w3.z;
        a3 += (double)xv.x * w0.w + (double)xv.y * w1.w
            + (double)xv.z * w2.w + (double)xv.w * w3.w;
    }
    #pragma unroll
    for (int off = 32; off > 0; off >>= 1) {
        a0 += __shfl_down(a0, off);
        a1 += __shfl_down(a1, off);
        a2 += __shfl_down(a2, off);
        a3 += __shfl_down(a3, off);
    }
    if (lane == 0) {
        double lg[4] = { a0 + (double)bg[0], a1 + (double)bg[1],
                         a2 + (double)bg[2], a3 + (double)bg[3] };
        int i1 = 0;
        for (int e = 1; e < 4; ++e) if (lg[e] > lg[i1]) i1 = e;   // first max wins
        int i2 = -1;
        for (int e = 0; e < 4; ++e) {
            if (e == i1) continue;
            if (i2 < 0 || lg[e] > lg[i2]) i2 = e;
        }
        int p1 = atomicAdd(&cnt[i1], 1);
        lists[i1 * NTOK + p1] = tok;
        int p2 = atomicAdd(&cnt[i2], 1);
        lists[i2 * NTOK + p2] = tok;
    }
}

// ---------------- prep: x fp32 -> fp16 ----------------
__global__ __launch_bounds__(256) void cvt_x_kernel(
    const float* __restrict__ x, _Float16* __restrict__ xh)
{
    size_t i = ((size_t)blockIdx.x * 256 + threadIdx.x) * 8;   // 8 elems/thread
    float4 v0 = *(const float4*)(x + i);
    float4 v1 = *(const float4*)(x + i + 4);
    half8_t h = { (_Float16)v0.x, (_Float16)v0.y, (_Float16)v0.z, (_Float16)v0.w,
                  (_Float16)v1.x, (_Float16)v1.y, (_Float16)v1.z, (_Float16)v1.w };
    *(half8_t*)(xh + i) = h;
}

// ---------------- prep: pack fp32 [z][R(k)][C(n)] into MFMA fragment tiles ----------
// Fragment (nb, kb) = 16 n-cols x 32 k-rows, 512 halves, stored so that
// half8 index (quad*16+ln) == lane: dst[frag*512 + quad*128 + ln*8 + j]
//   = src[kb*32 + quad*8 + j][nb*16 + ln]
__global__ __launch_bounds__(256) void tile_pack_kernel(
    const float* __restrict__ src, _Float16* __restrict__ dst, int R, int C)
{
    __shared__ _Float16 t2[32][36];     // [c_local][r_local]
    int r0 = blockIdx.y * 32, c0 = blockIdx.x * 32;
    const float* s = src + (size_t)blockIdx.z * R * C;
    _Float16* d = dst + (size_t)blockIdx.z * R * C;
    int tx = threadIdx.x & 31, ty = threadIdx.x >> 5;
    #pragma unroll
    for (int i = 0; i < 4; ++i) {
        int r = ty + i * 8;
        t2[tx][r] = (_Float16)s[(size_t)(r0 + r) * C + c0 + tx];
    }
    __syncthreads();
    int KB = R >> 5;
    int idx = threadIdx.x * 4;                 // 4 halves per thread
    int frag_h = idx >> 9;                     // which of the 2 n-frags in this 32-col block
    int rem = idx & 511;
    int quad = rem >> 7, ln = (rem >> 3) & 15, j0 = rem & 7;
    int cl = frag_h * 16 + ln, rl = quad * 8 + j0;
    half4_t v = { t2[cl][rl], t2[cl][rl + 1], t2[cl][rl + 2], t2[cl][rl + 3] };
    size_t off = ((size_t)(((c0 >> 4) + frag_h) * KB + (r0 >> 5))) * 512 + rem;
    *(half4_t*)&d[off] = v;
}

// ---------------- fast fused MLP: fragment-tiled fp16 weights ----------------
__global__ __launch_bounds__(512, 2) void moe_fast_kernel(
    const _Float16* __restrict__ xh, const _Float16* __restrict__ W1m,
    const float* __restrict__ b1, const _Float16* __restrict__ W2m,
    const float* __restrict__ b2, const int* __restrict__ cnt,
    const int* __restrict__ lists, float* __restrict__ out)
{
    __shared__ _Float16 Xs[MT][KC + 8];
    __shared__ _Float16 Hs[MT][FC + 8];
    __shared__ int tks[MT];

    int fhalf = blockIdx.x & 1;
    int bi = blockIdx.x >> 1;

    int expert = -1, tile = 0, mcnt = 0;
    int rem = bi;
    for (int e = 0; e < E_NUM; ++e) {
        int n = cnt[e];
        int nb = (n + MT - 1) / MT;
        if (rem < nb) { expert = e; tile = rem; mcnt = min(MT, n - rem * MT); break; }
        rem -= nb;
    }
    if (expert < 0) return;

    if (threadIdx.x < MT) {
        int idx = tile * MT + (int)threadIdx.x;
        tks[threadIdx.x] = lists[expert * NTOK + ((int)threadIdx.x < mcnt ? idx : tile * MT)];
    }
    __syncthreads();

    // fragment-tiled weight views (half8 units; frag stride = 64 half8s)
    const half8_t* W1f = (const half8_t*)(W1m + (size_t)expert * D_DIM * F_DIM);
    const half8_t* W2f = (const half8_t*)(W2m + (size_t)expert * D_DIM * F_DIM);
    const float* b1e = b1 + (size_t)expert * F_DIM;
    const float* b2e = b2 + (size_t)expert * D_DIM;

    int w = threadIdx.x >> 6;        // wave 0..7
    int lane = threadIdx.x & 63;
    int quad = lane >> 4;
    int ln = lane & 15;

    floatx4 oacc[4][8];
    #pragma unroll
    for (int mt = 0; mt < 4; ++mt)
        #pragma unroll
        for (int nt = 0; nt < 8; ++nt)
            oacc[mt][nt] = (floatx4){0.f, 0.f, 0.f, 0.f};

    int fbase = fhalf * FHALF;
    int srow = threadIdx.x >> 3;     // staging row 0..63
    int stg  = threadIdx.x & 7;      // 8 threads/row, 32 halves (64B) each

    for (int fc = 0; fc < FHALF / FC; ++fc) {
        int f0 = fbase + fc * FC;
        int fb0 = (f0 >> 4) + w * 2;          // GEMM1: wave covers f0+w*32 .. +32

        floatx4 hacc[4][2];
        #pragma unroll
        for (int mt = 0; mt < 4; ++mt) { hacc[mt][0] = (floatx4){0.f,0.f,0.f,0.f};
                                         hacc[mt][1] = (floatx4){0.f,0.f,0.f,0.f}; }

        for (int kc = 0; kc < D_DIM / KC; ++kc) {
            int k0 = kc * KC;
            // stage X chunk (fp16) -> LDS: 32 halves per thread
            {
                const _Float16* xr = xh + (size_t)tks[srow] * D_DIM + k0 + stg * 32;
                half8_t v0 = *(const half8_t*)(xr);
                half8_t v1 = *(const half8_t*)(xr + 8);
                half8_t v2 = *(const half8_t*)(xr + 16);
                half8_t v3 = *(const half8_t*)(xr + 24);
                *(half8_t*)&Xs[srow][stg * 32]      = v0;
                *(half8_t*)&Xs[srow][stg * 32 + 8]  = v1;
                *(half8_t*)&Xs[srow][stg * 32 + 16] = v2;
                *(half8_t*)&Xs[srow][stg * 32 + 24] = v3;
            }
            __syncthreads();

            #pragma unroll
            for (int ks = 0; ks < KC / 32; ++ks) {
                int kk = ks * 32 + quad * 8;
                int kb = kc * 8 + ks;                 // k-frag index (32-wide)
                half8_t a[4];
                #pragma unroll
                for (int mt = 0; mt < 4; ++mt)
                    a[mt] = *(const half8_t*)&Xs[mt * 16 + ln][kk];
                #pragma unroll
                for (int nt = 0; nt < 2; ++nt) {
                    // one contiguous 1KB fragment per wave, lane-linear
                    half8_t b = W1f[((size_t)((fb0 + nt) * 32 + kb)) * 64 + lane];
                    #pragma unroll
                    for (int mt = 0; mt < 4; ++mt)
                        hacc[mt][nt] = __builtin_amdgcn_mfma_f32_16x16x32_f16(
                            a[mt], b, hacc[mt][nt], 0, 0, 0);
                }
            }
            __syncthreads();
        }

        // bias + swish, H -> LDS (fp16)
        #pragma unroll
        for (int nt = 0; nt < 2; ++nt) {
            int fcol_l = w * 32 + nt * 16 + ln;
            float b1v = b1e[f0 + fcol_l];
            #pragma unroll
            for (int mt = 0; mt < 4; ++mt)
                #pragma unroll
                for (int r = 0; r < 4; ++r) {
                    float v = hacc[mt][nt][r] + b1v;
                    float hs = v / (1.f + __expf(-v));
                    Hs[mt * 16 + quad * 4 + r][fcol_l] = (_Float16)hs;
                }
        }
        __syncthreads();

        // GEMM2: Out += H @ W2[f-range, :]
        #pragma unroll
        for (int ks = 0; ks < FC / 32; ++ks) {
            int kk = ks * 32 + quad * 8;
            int fkb = (f0 >> 5) + ks;                 // k-frag index in f-dim
            half8_t a[4];
            #pragma unroll
            for (int mt = 0; mt < 4; ++mt)
                a[mt] = *(const half8_t*)&Hs[mt * 16 + ln][kk];
            #pragma unroll
            for (int nt = 0; nt < 8; ++nt) {
                int db = w * 8 + nt;                  // d-frag index (16-wide)
                half8_t b = W2f[((size_t)(db * 128 + fkb)) * 64 + lane];
                #pragma unroll
                for (int mt = 0; mt < 4; ++mt)
                    oacc[mt][nt] = __builtin_amdgcn_mfma_f32_16x16x32_f16(
                        a[mt], b, oacc[mt][nt], 0, 0, 0);
            }
        }
        __syncthreads();
    }

    // epilogue: scatter-add (each token has exactly 2 expert contributions)
    #pragma unroll
    for (int mt = 0; mt < 4; ++mt) {
        #pragma unroll
        for (int r = 0; r < 4; ++r) {
            int row = mt * 16 + quad * 4 + r;
            if (row >= mcnt) continue;
            float* orow = out + (size_t)tks[row] * D_DIM;
            #pragma unroll
            for (int nt = 0; nt < 8; ++nt) {
                int dcol = w * 128 + nt * 16 + ln;
                float v = oacc[mt][nt][r];
                if (fhalf == 0) v += b2e[dcol];   // bias exactly once per (tok,expert)
                atomicAdd(orow + dcol, v);
            }
        }
    }
}

// ---------------- fallback kernel: fp32 weights on the fly (ws too small) ----------
__global__ __launch_bounds__(512, 2) void moe_slow_kernel(
    const float* __restrict__ x, const float* __restrict__ W1,
    const float* __restrict__ b1, const float* __restrict__ W2,
    const float* __restrict__ b2, const int* __restrict__ cnt,
    const int* __restrict__ lists, float* __restrict__ out)
{
    __shared__ _Float16 Xs[MT][KC + 8];
    __shared__ _Float16 Hs[MT][FC + 8];
    __shared__ int tks[MT];

    int fhalf = blockIdx.x & 1;
    int bi = blockIdx.x >> 1;
    int expert = -1, tile = 0, mcnt = 0;
    int rem = bi;
    for (int e = 0; e < E_NUM; ++e) {
        int n = cnt[e];
        int nb = (n + MT - 1) / MT;
        if (rem < nb) { expert = e; tile = rem; mcnt = min(MT, n - rem * MT); break; }
        rem -= nb;
    }
    if (expert < 0) return;

    if (threadIdx.x < MT) {
        int idx = tile * MT + (int)threadIdx.x;
        tks[threadIdx.x] = lists[expert * NTOK + ((int)threadIdx.x < mcnt ? idx : tile * MT)];
    }
    __syncthreads();

    const float* W1e = W1 + (size_t)expert * D_DIM * F_DIM;
    const float* W2e = W2 + (size_t)expert * F_DIM * D_DIM;
    const float* b1e = b1 + (size_t)expert * F_DIM;
    const float* b2e = b2 + (size_t)expert * D_DIM;

    int w = threadIdx.x >> 6;
    int lane = threadIdx.x & 63;
    int quad = lane >> 4;
    int ln = lane & 15;

    floatx4 oacc[4][8];
    #pragma unroll
    for (int mt = 0; mt < 4; ++mt)
        #pragma unroll
        for (int nt = 0; nt < 8; ++nt)
            oacc[mt][nt] = (floatx4){0.f, 0.f, 0.f, 0.f};

    int fbase = fhalf * FHALF;
    int srow = threadIdx.x >> 3;
    int stg  = threadIdx.x & 7;

    for (int fc = 0; fc < FHALF / FC; ++fc) {
        int f0 = fbase + fc * FC;
        floatx4 hacc[4][2];
        #pragma unroll
        for (int mt = 0; mt < 4; ++mt) { hacc[mt][0] = (floatx4){0.f,0.f,0.f,0.f};
                                         hacc[mt][1] = (floatx4){0.f,0.f,0.f,0.f}; }
        for (int kc = 0; kc < D_DIM / KC; ++kc) {
            int k0 = kc * KC;
            {
                const float* xr = x + (size_t)tks[srow] * D_DIM + k0;
                #pragma unroll
                for (int j = 0; j < 8; ++j) {
                    int c = (stg + j * 8) * 4;
                    float4 v = *(const float4*)(xr + c);
                    half4_t hv = { (_Float16)v.x, (_Float16)v.y,
                                   (_Float16)v.z, (_Float16)v.w };
                    *(half4_t*)&Xs[srow][c] = hv;
                }
            }
            __syncthreads();
            #pragma unroll
            for (int ks = 0; ks < KC / 32; ++ks) {
                int kk = ks * 32 + quad * 8;
                half8_t a[4];
                #pragma unroll
                for (int mt = 0; mt < 4; ++mt)
                    a[mt] = *(const half8_t*)&Xs[mt * 16 + ln][kk];
                #pragma unroll
                for (int nt = 0; nt < 2; ++nt) {
                    int fcol = f0 + w * 32 + nt * 16 + ln;
                    const float* wp = W1e + (size_t)(k0 + kk) * F_DIM + fcol;
                    half8_t b;
                    #pragma unroll
                    for (int j = 0; j < 8; ++j)
                        b[j] = (_Float16)wp[(size_t)j * F_DIM];
                    #pragma unroll
                    for (int mt = 0; mt < 4; ++mt)
                        hacc[mt][nt] = __builtin_amdgcn_mfma_f32_16x16x32_f16(
                            a[mt], b, hacc[mt][nt], 0, 0, 0);
                }
            }
            __syncthreads();
        }
        #pragma unroll
        for (int nt = 0; nt < 2; ++nt) {
            int fcol_l = w * 32 + nt * 16 + ln;
            float b1v = b1e[f0 + fcol_l];
            #pragma unroll
            for (int mt = 0; mt < 4; ++mt)
                #pragma unroll
                for (int r = 0; r < 4; ++r) {
                    float v = hacc[mt][nt][r] + b1v;
                    float hs = v / (1.f + __expf(-v));
                    Hs[mt * 16 + quad * 4 + r][fcol_l] = (_Float16)hs;
                }
        }
        __syncthreads();
        #pragma unroll
        for (int ks = 0; ks < FC / 32; ++ks) {
            int kk = ks * 32 + quad * 8;
            half8_t a[4];
            #pragma unroll
            for (int mt = 0; mt < 4; ++mt)
                a[mt] = *(const half8_t*)&Hs[mt * 16 + ln][kk];
            #pragma unroll
            for (int nt = 0; nt < 8; ++nt) {
                int dcol = w * 128 + nt * 16 + ln;
                const float* wp = W2e + (size_t)(f0 + kk) * D_DIM + dcol;
                half8_t b;
                #pragma unroll
                for (int j = 0; j < 8; ++j)
                    b[j] = (_Float16)wp[(size_t)j * D_DIM];
                #pragma unroll
                for (int mt = 0; mt < 4; ++mt)
                    oacc[mt][nt] = __builtin_amdgcn_mfma_f32_16x16x32_f16(
                        a[mt], b, oacc[mt][nt], 0, 0, 0);
            }
        }
        __syncthreads();
    }
    #pragma unroll
    for (int mt = 0; mt < 4; ++mt) {
        #pragma unroll
        for (int r = 0; r < 4; ++r) {
            int row = mt * 16 + quad * 4 + r;
            if (row >= mcnt) continue;
            float* orow = out + (size_t)tks[row] * D_DIM;
            #pragma unroll
            for (int nt = 0; nt < 8; ++nt) {
                int dcol = w * 128 + nt * 16 + ln;
                float v = oacc[mt][nt][r];
                if (fhalf == 0) v += b2e[dcol];
                atomicAdd(orow + dcol, v);
            }
        }
    }
}

extern "C" void kernel_launch(void* const* d_in, const int* in_sizes, int n_in,
                              void* d_out, int out_size, void* d_ws, size_t ws_size,
                              hipStream_t stream) {
    const float* x  = (const float*)d_in[0];
    const float* Wg = (const float*)d_in[1];
    const float* bg = (const float*)d_in[2];
    const float* W1 = (const float*)d_in[3];
    const float* b1 = (const float*)d_in[4];
    const float* W2 = (const float*)d_in[5];
    const float* b2 = (const float*)d_in[6];
    float* out = (float*)d_out;

    // ws layout: [cnt 16B][pad][lists @512B, 128KB][W1m 32MB][W2m 32MB][xh 16MB]
    const size_t OFF_LISTS = 512;
    const size_t OFF_W1M   = 131584;                       // 512 + 4*8192*4
    const size_t OFF_W2M   = OFF_W1M + (size_t)E_NUM * D_DIM * F_DIM * 2;
    const size_t OFF_XH    = OFF_W2M + (size_t)E_NUM * D_DIM * F_DIM * 2;
    const size_t WS_NEED   = OFF_XH + (size_t)NTOK * D_DIM * 2;

    int* cnt   = (int*)d_ws;
    int* lists = (int*)((char*)d_ws + OFF_LISTS);

    hipMemsetAsync(cnt, 0, 16, stream);
    hipMemsetAsync(d_out, 0, (size_t)out_size * sizeof(float), stream);

    gate_kernel<<<NTOK / 4, 256, 0, stream>>>(x, Wg, bg, cnt, lists);

    if (ws_size >= WS_NEED) {
        _Float16* W1m = (_Float16*)((char*)d_ws + OFF_W1M);
        _Float16* W2m = (_Float16*)((char*)d_ws + OFF_W2M);
        _Float16* xh  = (_Float16*)((char*)d_ws + OFF_XH);

        cvt_x_kernel<<<(NTOK * D_DIM) / (256 * 8), 256, 0, stream>>>(x, xh);
        // W1 [E][D(k)][F(n)] -> fragment tiles (NB=F/16, KB=D/32)
        tile_pack_kernel<<<dim3(F_DIM / 32, D_DIM / 32, E_NUM), 256, 0, stream>>>(
            W1, W1m, D_DIM, F_DIM);
        // W2 [E][F(k)][D(n)] -> fragment tiles (NB=D/16, KB=F/32)
        tile_pack_kernel<<<dim3(D_DIM / 32, F_DIM / 32, E_NUM), 256, 0, stream>>>(
            W2, W2m, F_DIM, D_DIM);

        moe_fast_kernel<<<520, 512, 0, stream>>>(xh, W1m, b1, W2m, b2, cnt, lists, out);
    } else {
        moe_slow_kernel<<<520, 512, 0, stream>>>(x, W1, b1, W2, b2, cnt, lists, out);
    }
}